// Round 3
// baseline (178.106 us; speedup 1.0000x reference)
//
#include <hip/hip_runtime.h>
#include <hip/hip_bf16.h>

// ClusterLoss fused kernel for MI355X (gfx950).  R10.
// = R9 structure (B split into two 512-center halves, 64-row A tiles,
// 77.8 KB LDS -> 2 blocks/CU -> 4 waves/SIMD) with the ONE-LINE fix:
// __launch_bounds__(512, 1).  R9's (512,4) made the backend pin VGPR=64
// and spill 10.3 MB of accumulators to scratch (WRITE_SIZE tripwire).
// Confirmed allocator rules on this kernel:
//   1024-thread block        -> 64 VGPR pin + spill   (R8)
//   512-thread, min-waves>=4 -> 64 VGPR pin + spill   (R9)
//   512-thread, min-waves=1  -> ~100 VGPR, no spill   (R4/R7)
// Occupancy comes from LDS sizing only.
// loss_n = 1 - 2 d na/nf + na^2 (fp32 scalars).

#define D 128
#define NK 1024
#define HALFK 512
#define ROWT 64

typedef __attribute__((ext_vector_type(4))) float floatx4;

template <bool HI>
__device__ __forceinline__ unsigned int pk_fp8(float a, float b, unsigned int old) {
    return (unsigned int)__builtin_amdgcn_cvt_pk_fp8_f32(a, b, (int)old, HI);
}

__device__ __forceinline__ float key_pack(float v, unsigned int inv_k) {
    unsigned int u = __builtin_bit_cast(unsigned int, v);
    unsigned int r = (0x3FFu & inv_k) | (~0x3FFu & u);   // v_bfi_b32
    return __builtin_bit_cast(float, r);
}

// ---- Prep: normalize centers -> fp8 chat, store fp32 norms; zero d_out ----
__global__ void prep_centers(const float* __restrict__ centers,
                             unsigned char* __restrict__ chat,
                             float* __restrict__ cnorm,
                             float* __restrict__ out) {
    const int k = blockIdx.x;
    const int t = threadIdx.x;            // 128 threads, one per dim
    float v = centers[(size_t)k * D + t];
    float s = v * v;
    #pragma unroll
    for (int m = 1; m <= 32; m <<= 1) s += __shfl_xor(s, m);
    __shared__ float ws2[2];
    if ((t & 63) == 0) ws2[t >> 6] = s;
    __syncthreads();
    float total = ws2[0] + ws2[1];
    float n = sqrtf(total);
    float neff = fmaxf(n, 1e-12f);
    float q = v / neff;
    chat[(size_t)k * D + t] = (unsigned char)(pk_fp8<false>(q, q, 0u) & 0xFFu);
    if (t == 0) cnorm[k] = n;
    if (k == 0 && t == 0) out[0] = 0.0f;
}

// ---- Main ----
__global__ __launch_bounds__(512, 1) void cluster_main(
    const float* __restrict__ feats,        // [N][128] fp32
    const unsigned char* __restrict__ chat, // [1024][128] fp8 e4m3
    const float* __restrict__ cnorm,        // [1024] fp32
    float* __restrict__ out, int N, int rtPer) {

    extern __shared__ unsigned char lds[];
    unsigned char* Bs = lds;                 // 65536 B, swizzled (512 centers)
    unsigned char* As = lds + HALFK * D;     // 8192 B, swizzled (64 rows)
    __shared__ float nf_s[256];              // per-row sumsq (block's 256 rows)
    __shared__ float best_s[256];            // running keyed max across halves
    __shared__ float bv[8][64];              // per-wave keyed max per row

    const int tid  = threadIdx.x;            // 0..511, 8 waves
    const int lane = tid & 63;
    const int wn   = tid >> 6;               // wave = col slice (64 centers)
    const int m16  = lane & 15;
    const int quad = lane >> 4;              // 0..3
    const int q1   = quad >> 1, q0 = quad & 1;
    const int m8   = m16 & 7;
    const int rowBase = blockIdx.x * (rtPer * ROWT);

    for (int half = 0; half < 2; ++half) {
        // ---- Stage B half: 4096 16B chunks, 8/thread, swizzled ----
        #pragma unroll
        for (int s = 0; s < 8; ++s) {
            int id = s * 512 + tid;
            int r  = id >> 3;                // local center row 0..511
            int c  = id & 7;                 // logical 16B chunk
            uint4 v = *(const uint4*)(chat + (size_t)(half * HALFK + r) * D + c * 16);
            *(uint4*)&Bs[r * D + ((c ^ (r & 7)) << 4)] = v;
        }

        for (int rt = 0; rt < rtPer; ++rt) {
            const int row0 = rowBase + rt * ROWT;

            // ---- Stage A (coalesced float4 -> fp8, swizzled) + row sumsq ----
            #pragma unroll
            for (int s = 0; s < 4; ++s) {
                int id = s * 512 + tid;      // float4 chunk, 0..2047
                int r  = id >> 5;            // local row 0..63
                int c4 = id & 31;
                float4 v = *(const float4*)(feats + (size_t)(row0 + r) * D + c4 * 4);
                unsigned int w = pk_fp8<false>(v.x, v.y, 0u);
                w = pk_fp8<true>(v.z, v.w, w);
                int pc = (c4 >> 2) ^ (r & 7);
                *(unsigned int*)&As[r * D + pc * 16 + (c4 & 3) * 4] = w;
                float sq = v.x*v.x + v.y*v.y + v.z*v.z + v.w*v.w;
                #pragma unroll
                for (int m = 1; m <= 16; m <<= 1) sq += __shfl_xor(sq, m);
                if ((tid & 31) == 0) nf_s[rt * ROWT + r] = sq;
            }
            __syncthreads();                 // Bs + As + nf_s visible

            // ---- A fragments from LDS ----
            long long afr[4][4];             // [i][kk], i covers 64 rows
            #pragma unroll
            for (int i = 0; i < 4; ++i) {
                const int r = i * 16 + m16;
                #pragma unroll
                for (int kk = 0; kk < 4; ++kk) {
                    int pc = (2 * kk + q1) ^ m8;
                    afr[i][kk] = *(const long long*)&As[r * D + pc * 16 + q0 * 8];
                }
            }

            float best[16];                  // keyed floats, per (i,r) slot
            #pragma unroll
            for (int s = 0; s < 16; ++s) best[s] = -3.0e38f;

            // ---- barrier-free MFMA over this wave's 64-center slice ----
            #pragma unroll
            for (int ch = 0; ch < 2; ++ch) { // 2 chunks of 32 centers
                const int cl = wn * 64 + ch * 32;    // local center base
                const unsigned int inv0 =
                    1023u - (unsigned)(half * HALFK + cl + m16);     // j=0
                const unsigned int inv1 = inv0 - 16u;                // j=1
                floatx4 acc[4][2];
                #pragma unroll
                for (int i = 0; i < 4; ++i)
                    #pragma unroll
                    for (int j = 0; j < 2; ++j)
                        acc[i][j] = (floatx4){0.f, 0.f, 0.f, 0.f};

                #pragma unroll
                for (int kk = 0; kk < 4; ++kk) {
                    long long bfr[2];
                    #pragma unroll
                    for (int j = 0; j < 2; ++j) {
                        int k  = cl + j * 16 + m16;
                        int pc = (2 * kk + q1) ^ m8;
                        bfr[j] = *(const long long*)&Bs[k * D + pc * 16 + q0 * 8];
                    }
                    #pragma unroll
                    for (int i = 0; i < 4; ++i)
                        #pragma unroll
                        for (int j = 0; j < 2; ++j)
                            acc[i][j] = __builtin_amdgcn_mfma_f32_16x16x32_fp8_fp8(
                                afr[i][kk], bfr[j], acc[i][j], 0, 0, 0);
                }

                // keyed argmax: bfi + max per candidate pair
                #pragma unroll
                for (int i = 0; i < 4; ++i)
                    #pragma unroll
                    for (int r = 0; r < 4; ++r) {
                        const int slot = i * 4 + r;
                        float c0 = key_pack(acc[i][0][r], inv0);
                        float c1 = key_pack(acc[i][1][r], inv1);
                        best[slot] = fmaxf(best[slot], fmaxf(c0, c1));
                    }
            }

            // cross-m16 butterfly (same rows, different cols)
            #pragma unroll
            for (int mask = 1; mask <= 8; mask <<= 1)
                #pragma unroll
                for (int s = 0; s < 16; ++s)
                    best[s] = fmaxf(best[s], __shfl_xor(best[s], mask));

            if (m16 == 0) {
                #pragma unroll
                for (int s = 0; s < 16; ++s) {
                    int i = s >> 2, rr = s & 3;
                    int row = 16 * i + quad * 4 + rr;   // local row 0..63
                    bv[wn][row] = best[s];
                }
            }
            __syncthreads();                 // bv visible; all As/Bs reads done

            // ---- combine 8 col-slices into running per-row best ----
            if (tid < 64) {
                float k01 = fmaxf(bv[0][tid], bv[1][tid]);
                float k23 = fmaxf(bv[2][tid], bv[3][tid]);
                float k45 = fmaxf(bv[4][tid], bv[5][tid]);
                float k67 = fmaxf(bv[6][tid], bv[7][tid]);
                float kmax = fmaxf(fmaxf(k01, k23), fmaxf(k45, k67));
                int idx = rt * ROWT + tid;
                best_s[idx] = (half == 0) ? kmax : fmaxf(best_s[idx], kmax);
            }
            // no trailing barrier needed: next phase writes As/nf_s/Bs only,
            // disjoint from bv/best_s read here; bv rewritten only after the
            // next __syncthreads().
        }
    }

    __syncthreads();                         // best_s final + visible

    // ---- decode; loss; reduce (256 rows, 4 waves) ----
    if (tid < 256) {
        const int row = tid;
        unsigned int ub = __builtin_bit_cast(unsigned int, best_s[row]);
        int   ka = 1023 - (int)(ub & 1023u);
        float d  = __builtin_bit_cast(float, (ub & 0xFFFFFC00u) | 0x200u);
        float nf = fmaxf(sqrtf(nf_s[row]), 1e-12f);
        float na = cnorm[ka];
        float lsum = 1.0f - 2.0f * d * na / nf + na * na;
        #pragma unroll
        for (int m = 1; m <= 32; m <<= 1) lsum += __shfl_xor(lsum, m);
        if (lane == 0) atomicAdd(out, lsum / (float)N);
    }
}

extern "C" void kernel_launch(void* const* d_in, const int* in_sizes, int n_in,
                              void* d_out, int out_size, void* d_ws, size_t ws_size,
                              hipStream_t stream) {
    const float* feats   = (const float*)d_in[0];
    const float* centers = (const float*)d_in[1];
    const int N = in_sizes[0] / D;   // 131072
    const int K = in_sizes[1] / D;   // 1024

    unsigned char* chat = (unsigned char*)d_ws;                    // 1024*128 fp8 = 128 KB
    float* cnorm = (float*)((char*)d_ws + (size_t)K * D);          // K fp32
    float* out = (float*)d_out;

    const int smem = HALFK * D + ROWT * D;   // 73728 B dynamic (77.8 KB w/ static)
    (void)hipFuncSetAttribute((const void*)cluster_main,
                              hipFuncAttributeMaxDynamicSharedMemorySize, smem);

    prep_centers<<<K, D, 0, stream>>>(centers, chat, cnorm, out);

    const int grid = 512;                    // 2 blocks/CU x 256 CU
    const int rtPer = (N / ROWT) / grid;     // 4 row tiles of 64
    cluster_main<<<grid, 512, smem, stream>>>(feats, chat, cnorm, out, N, rtPer);
}

// Round 4
// 161.451 us; speedup vs baseline: 1.1032x; 1.1032x over previous
//
#include <hip/hip_runtime.h>
#include <hip/hip_bf16.h>

// ClusterLoss fused kernel for MI355X (gfx950).  R11.
// Key change vs R7-R10: B (normalized centers, fp8) lives in REGISTERS, not
// LDS. The 16x16x32 fp8 B-fragment is 8 B/lane at chat[center][kk*32+quad*8]
// -> loaded directly from global (chat is 128 KB, L2-hot), no swizzle, no
// staging loop, no B-side ds_reads. Each wave owns a 64-center slice
// (16 x long long = 32 VGPRs); two center-half passes with a running keyed
// max in LDS (best_s, verified in R9/R10) cover all 1024 centers.
// LDS drops 147 KB -> 12 KB, so co-residency is gated only by VGPR (~100
// regs -> 2 blocks/CU, 4 waves/SIMD). R7's stall (MfmaUtil 18%, 4x over the
// 16.8 us MFMA floor) was latency with 2 waves/SIMD; this doubles the
// latency-hiding without touching the verified math.
// Allocator rules (measured): 1024-thread or min-waves>=4 -> 64-VGPR pin +
// spill. Stay at 512 threads, __launch_bounds__(512, 1).
// loss_n = 1 - 2 d na/nf + na^2 (fp32 scalars).

#define D 128
#define ROWT 64

typedef __attribute__((ext_vector_type(4))) float floatx4;

template <bool HI>
__device__ __forceinline__ unsigned int pk_fp8(float a, float b, unsigned int old) {
    return (unsigned int)__builtin_amdgcn_cvt_pk_fp8_f32(a, b, (int)old, HI);
}

__device__ __forceinline__ float key_pack(float v, unsigned int inv_k) {
    unsigned int u = __builtin_bit_cast(unsigned int, v);
    unsigned int r = (0x3FFu & inv_k) | (~0x3FFu & u);   // v_bfi_b32
    return __builtin_bit_cast(float, r);
}

// ---- Prep: normalize centers -> fp8 chat, store fp32 norms; zero d_out ----
__global__ void prep_centers(const float* __restrict__ centers,
                             unsigned char* __restrict__ chat,
                             float* __restrict__ cnorm,
                             float* __restrict__ out) {
    const int k = blockIdx.x;
    const int t = threadIdx.x;            // 128 threads, one per dim
    float v = centers[(size_t)k * D + t];
    float s = v * v;
    #pragma unroll
    for (int m = 1; m <= 32; m <<= 1) s += __shfl_xor(s, m);
    __shared__ float ws2[2];
    if ((t & 63) == 0) ws2[t >> 6] = s;
    __syncthreads();
    float total = ws2[0] + ws2[1];
    float n = sqrtf(total);
    float neff = fmaxf(n, 1e-12f);
    float q = v / neff;
    chat[(size_t)k * D + t] = (unsigned char)(pk_fp8<false>(q, q, 0u) & 0xFFu);
    if (t == 0) cnorm[k] = n;
    if (k == 0 && t == 0) out[0] = 0.0f;
}

// ---- Main ----
__global__ __launch_bounds__(512, 1) void cluster_main(
    const float* __restrict__ feats,        // [N][128] fp32
    const unsigned char* __restrict__ chat, // [1024][128] fp8 e4m3
    const float* __restrict__ cnorm,        // [1024] fp32
    float* __restrict__ out, int N, int rtPer) {

    extern __shared__ unsigned char lds[];
    unsigned char* As = lds;                 // 8192 B, swizzled (64 rows)
    __shared__ float nf_s[256];              // per-row sumsq (block's 256 rows)
    __shared__ float best_s[256];            // running keyed max across halves
    __shared__ float bv[8][64];              // per-wave keyed max per row

    const int tid  = threadIdx.x;            // 0..511, 8 waves
    const int lane = tid & 63;
    const int wn   = tid >> 6;               // wave = 64-center slice
    const int m16  = lane & 15;
    const int quad = lane >> 4;              // 0..3
    const int q1   = quad >> 1, q0 = quad & 1;
    const int m8   = m16 & 7;
    const int rowBase = blockIdx.x * (rtPer * ROWT);

    #pragma unroll 1
    for (int half = 0; half < 2; ++half) {
        // ---- Load this wave's 64-center B slice into registers ----
        // frag(j,kk) = 8B at chat[c0h + j*16 + m16][kk*32 + quad*8]
        const int c0h = half * 512 + wn * 64;
        long long breg[4][4];
        #pragma unroll
        for (int j = 0; j < 4; ++j)
            #pragma unroll
            for (int kk = 0; kk < 4; ++kk)
                breg[j][kk] = *(const long long*)(chat
                    + (size_t)(c0h + j * 16 + m16) * D + kk * 32 + quad * 8);

        #pragma unroll 1
        for (int rt = 0; rt < rtPer; ++rt) {
            const int row0 = rowBase + rt * ROWT;

            // ---- Stage A (coalesced float4 -> fp8, swizzled) + row sumsq ----
            #pragma unroll
            for (int s = 0; s < 4; ++s) {
                int id = s * 512 + tid;      // float4 chunk, 0..2047
                int r  = id >> 5;            // local row 0..63
                int c4 = id & 31;
                float4 v = *(const float4*)(feats + (size_t)(row0 + r) * D + c4 * 4);
                unsigned int w = pk_fp8<false>(v.x, v.y, 0u);
                w = pk_fp8<true>(v.z, v.w, w);
                int pc = (c4 >> 2) ^ (r & 7);
                *(unsigned int*)&As[r * D + pc * 16 + (c4 & 3) * 4] = w;
                float sq = v.x*v.x + v.y*v.y + v.z*v.z + v.w*v.w;
                #pragma unroll
                for (int m = 1; m <= 16; m <<= 1) sq += __shfl_xor(sq, m);
                if ((tid & 31) == 0) nf_s[rt * ROWT + r] = sq;
            }
            __syncthreads();                 // As + nf_s visible

            float best[16];                  // keyed floats, slot = i*4 + r
            #pragma unroll
            for (int s = 0; s < 16; ++s) best[s] = -3.0e38f;

            // ---- barrier-free MFMA: 64 rows x this wave's 64 centers ----
            #pragma unroll
            for (int ihalf = 0; ihalf < 2; ++ihalf) {
                long long afr[2][4];         // [i2][kk]
                #pragma unroll
                for (int i2 = 0; i2 < 2; ++i2) {
                    const int r = (ihalf * 2 + i2) * 16 + m16;
                    #pragma unroll
                    for (int kk = 0; kk < 4; ++kk) {
                        int pc = (2 * kk + q1) ^ m8;
                        afr[i2][kk] = *(const long long*)&As[r * D + pc * 16 + q0 * 8];
                    }
                }
                #pragma unroll
                for (int jp = 0; jp < 2; ++jp) {
                    floatx4 acc[2][2];
                    #pragma unroll
                    for (int i2 = 0; i2 < 2; ++i2)
                        #pragma unroll
                        for (int j2 = 0; j2 < 2; ++j2)
                            acc[i2][j2] = (floatx4){0.f, 0.f, 0.f, 0.f};
                    #pragma unroll
                    for (int kk = 0; kk < 4; ++kk)
                        #pragma unroll
                        for (int i2 = 0; i2 < 2; ++i2)
                            #pragma unroll
                            for (int j2 = 0; j2 < 2; ++j2)
                                acc[i2][j2] = __builtin_amdgcn_mfma_f32_16x16x32_fp8_fp8(
                                    afr[i2][kk], breg[jp * 2 + j2][kk], acc[i2][j2], 0, 0, 0);

                    const unsigned int inv0 = 1023u - (unsigned)(c0h + jp * 32 + m16);
                    const unsigned int inv1 = inv0 - 16u;
                    #pragma unroll
                    for (int i2 = 0; i2 < 2; ++i2)
                        #pragma unroll
                        for (int r = 0; r < 4; ++r) {
                            const int slot = (ihalf * 2 + i2) * 4 + r;
                            float cc0 = key_pack(acc[i2][0][r], inv0);
                            float cc1 = key_pack(acc[i2][1][r], inv1);
                            best[slot] = fmaxf(best[slot], fmaxf(cc0, cc1));
                        }
                }
            }

            // cross-m16 butterfly (same rows, different cols)
            #pragma unroll
            for (int mask = 1; mask <= 8; mask <<= 1)
                #pragma unroll
                for (int s = 0; s < 16; ++s)
                    best[s] = fmaxf(best[s], __shfl_xor(best[s], mask));

            if (m16 == 0) {
                #pragma unroll
                for (int s = 0; s < 16; ++s) {
                    int i = s >> 2, rr = s & 3;
                    int row = 16 * i + quad * 4 + rr;   // local row 0..63
                    bv[wn][row] = best[s];
                }
            }
            __syncthreads();                 // bv visible; all As reads done

            // ---- combine 8 wave-slices into running per-row best ----
            if (tid < 64) {
                float k01 = fmaxf(bv[0][tid], bv[1][tid]);
                float k23 = fmaxf(bv[2][tid], bv[3][tid]);
                float k45 = fmaxf(bv[4][tid], bv[5][tid]);
                float k67 = fmaxf(bv[6][tid], bv[7][tid]);
                float kmax = fmaxf(fmaxf(k01, k23), fmaxf(k45, k67));
                int idx = rt * ROWT + tid;
                best_s[idx] = (half == 0) ? kmax : fmaxf(best_s[idx], kmax);
            }
            // no trailing barrier: next iter writes As/nf_s (disjoint from
            // bv/best_s read here); bv rewritten only after next barrier.
        }
    }

    __syncthreads();                         // best_s final + visible

    // ---- decode; loss; reduce (256 rows, 4 waves) ----
    if (tid < 256) {
        const int row = tid;
        unsigned int ub = __builtin_bit_cast(unsigned int, best_s[row]);
        int   ka = 1023 - (int)(ub & 1023u);
        float d  = __builtin_bit_cast(float, (ub & 0xFFFFFC00u) | 0x200u);
        float nf = fmaxf(sqrtf(nf_s[row]), 1e-12f);
        float na = cnorm[ka];
        float lsum = 1.0f - 2.0f * d * na / nf + na * na;
        #pragma unroll
        for (int m = 1; m <= 32; m <<= 1) lsum += __shfl_xor(lsum, m);
        if (lane == 0) atomicAdd(out, lsum / (float)N);
    }
}

extern "C" void kernel_launch(void* const* d_in, const int* in_sizes, int n_in,
                              void* d_out, int out_size, void* d_ws, size_t ws_size,
                              hipStream_t stream) {
    const float* feats   = (const float*)d_in[0];
    const float* centers = (const float*)d_in[1];
    const int N = in_sizes[0] / D;   // 131072
    const int K = in_sizes[1] / D;   // 1024

    unsigned char* chat = (unsigned char*)d_ws;                    // 1024*128 fp8 = 128 KB
    float* cnorm = (float*)((char*)d_ws + (size_t)K * D);          // K fp32
    float* out = (float*)d_out;

    const int smem = ROWT * D;               // 8192 B dynamic (~12.3 KB total)
    (void)hipFuncSetAttribute((const void*)cluster_main,
                              hipFuncAttributeMaxDynamicSharedMemorySize, smem);

    prep_centers<<<K, D, 0, stream>>>(centers, chat, cnorm, out);

    const int grid = 512;                    // 256 rows/block
    const int rtPer = (N / ROWT) / grid;     // 4 row tiles of 64
    cluster_main<<<grid, 512, smem, stream>>>(feats, chat, cnorm, out, N, rtPer);
}

// Round 5
// 144.255 us; speedup vs baseline: 1.2347x; 1.1192x over previous
//
#include <hip/hip_runtime.h>
#include <hip/hip_bf16.h>

// ClusterLoss fused kernel for MI355X (gfx950).  R12.
// Post-mortem R11: half-loop OUTSIDE rt doubled A-staging (the VALU+shuffle
// heavy phase) and feats HBM reads -> 26 us VALU vs 16.6 us MFMA floor.
// R12: single pass over rows. Per row-tile: stage A ONCE, then two B-half
// passes with B fragments in registers (reloaded from L2-hot chat, 8 KB/wave).
//   - staging rebuilt: thread = one (row, 16B fp8 chunk); 16 consecutive
//     floats of one row -> lane-local sumsq (zero shuffles), one
//     ds_write_b128; wave reads 8 full rows contiguously (coalesced).
//   - per-thread sumsq partials -> nfp[rt&1][] (parity dbuf); summed in the
//     tid<64 combine step, which also decodes argmax and computes the loss
//     directly (best_s / nf_s / final phase deleted).
// LDS 14 KB -> co-residency gated only by VGPR (~100 regs -> 2 blocks/CU,
// 4 waves/SIMD).
// Allocator rules (measured): 1024-thread or min-waves>=4 -> 64-VGPR pin +
// spill. Stay at 512 threads, __launch_bounds__(512, 1).
// loss_n = 1 - 2 d na/nf + na^2 (fp32 scalars).

#define D 128
#define ROWT 64

typedef __attribute__((ext_vector_type(4))) float floatx4;

template <bool HI>
__device__ __forceinline__ unsigned int pk_fp8(float a, float b, unsigned int old) {
    return (unsigned int)__builtin_amdgcn_cvt_pk_fp8_f32(a, b, (int)old, HI);
}

__device__ __forceinline__ float key_pack(float v, unsigned int inv_k) {
    unsigned int u = __builtin_bit_cast(unsigned int, v);
    unsigned int r = (0x3FFu & inv_k) | (~0x3FFu & u);   // v_bfi_b32
    return __builtin_bit_cast(float, r);
}

// ---- Prep: normalize centers -> fp8 chat, store fp32 norms; zero d_out ----
__global__ void prep_centers(const float* __restrict__ centers,
                             unsigned char* __restrict__ chat,
                             float* __restrict__ cnorm,
                             float* __restrict__ out) {
    const int k = blockIdx.x;
    const int t = threadIdx.x;            // 128 threads, one per dim
    float v = centers[(size_t)k * D + t];
    float s = v * v;
    #pragma unroll
    for (int m = 1; m <= 32; m <<= 1) s += __shfl_xor(s, m);
    __shared__ float ws2[2];
    if ((t & 63) == 0) ws2[t >> 6] = s;
    __syncthreads();
    float total = ws2[0] + ws2[1];
    float n = sqrtf(total);
    float neff = fmaxf(n, 1e-12f);
    float q = v / neff;
    chat[(size_t)k * D + t] = (unsigned char)(pk_fp8<false>(q, q, 0u) & 0xFFu);
    if (t == 0) cnorm[k] = n;
    if (k == 0 && t == 0) out[0] = 0.0f;
}

// ---- Main ----
__global__ __launch_bounds__(512, 1) void cluster_main(
    const float* __restrict__ feats,        // [N][128] fp32
    const unsigned char* __restrict__ chat, // [1024][128] fp8 e4m3
    const float* __restrict__ cnorm,        // [1024] fp32
    float* __restrict__ out, int N, int rtPer) {

    extern __shared__ unsigned char lds[];
    unsigned char* As = lds;                 // 8192 B, swizzled (64 rows)
    __shared__ float bv[8][64];              // per-wave keyed max per row
    __shared__ float nfp[2][512];            // sumsq partials, rt-parity dbuf

    const int tid  = threadIdx.x;            // 0..511, 8 waves
    const int lane = tid & 63;
    const int wn   = tid >> 6;               // wave = 64-center slice
    const int m16  = lane & 15;
    const int quad = lane >> 4;              // 0..3
    const int q1   = quad >> 1, q0 = quad & 1;
    const int m8   = m16 & 7;
    const int rowBase = blockIdx.x * (rtPer * ROWT);
    const int sr = tid >> 3;                 // staging row 0..63
    const int sc = tid & 7;                  // staging 16B fp8 chunk 0..7

    long long breg[4][4];                    // this wave's 64-center B slice

    #pragma unroll 1
    for (int rt = 0; rt < rtPer; ++rt) {
        const int row0 = rowBase + rt * ROWT;

        // ---- Stage A: 1 thread = 1 (row, chunk); zero cross-lane ops ----
        {
            const float4* src =
                (const float4*)(feats + (size_t)(row0 + sr) * D + sc * 16);
            float4 v0 = src[0], v1 = src[1], v2 = src[2], v3 = src[3];
            uint4 w;
            w.x = pk_fp8<true>(v0.z, v0.w, pk_fp8<false>(v0.x, v0.y, 0u));
            w.y = pk_fp8<true>(v1.z, v1.w, pk_fp8<false>(v1.x, v1.y, 0u));
            w.z = pk_fp8<true>(v2.z, v2.w, pk_fp8<false>(v2.x, v2.y, 0u));
            w.w = pk_fp8<true>(v3.z, v3.w, pk_fp8<false>(v3.x, v3.y, 0u));
            *(uint4*)&As[sr * D + ((sc ^ (sr & 7)) << 4)] = w;
            float sq = v0.x*v0.x + v0.y*v0.y + v0.z*v0.z + v0.w*v0.w;
            sq += v1.x*v1.x + v1.y*v1.y + v1.z*v1.z + v1.w*v1.w;
            sq += v2.x*v2.x + v2.y*v2.y + v2.z*v2.z + v2.w*v2.w;
            sq += v3.x*v3.x + v3.y*v3.y + v3.z*v3.z + v3.w*v3.w;
            nfp[rt & 1][tid] = sq;
        }

        // ---- breg for half 0 (issued pre-barrier: overlaps staging drain) ----
        {
            const int c0h = wn * 64;
            #pragma unroll
            for (int j = 0; j < 4; ++j)
                #pragma unroll
                for (int kk = 0; kk < 4; ++kk)
                    breg[j][kk] = *(const long long*)(chat
                        + (size_t)(c0h + j * 16 + m16) * D + kk * 32 + quad * 8);
        }
        __syncthreads();                     // As + nfp visible

        float best[16];                      // keyed floats, slot = i*4 + r
        #pragma unroll
        for (int s = 0; s < 16; ++s) best[s] = -3.0e38f;

        // ---- two center-half passes, barrier-free ----
        #pragma unroll
        for (int half = 0; half < 2; ++half) {
            const int c0h = half * 512 + wn * 64;
            if (half) {
                #pragma unroll
                for (int j = 0; j < 4; ++j)
                    #pragma unroll
                    for (int kk = 0; kk < 4; ++kk)
                        breg[j][kk] = *(const long long*)(chat
                            + (size_t)(c0h + j * 16 + m16) * D + kk * 32 + quad * 8);
            }

            #pragma unroll
            for (int ihalf = 0; ihalf < 2; ++ihalf) {
                long long afr[2][4];         // [i2][kk]
                #pragma unroll
                for (int i2 = 0; i2 < 2; ++i2) {
                    const int r = (ihalf * 2 + i2) * 16 + m16;
                    #pragma unroll
                    for (int kk = 0; kk < 4; ++kk) {
                        int pc = (2 * kk + q1) ^ m8;
                        afr[i2][kk] = *(const long long*)&As[r * D + pc * 16 + q0 * 8];
                    }
                }
                #pragma unroll
                for (int jp = 0; jp < 2; ++jp) {
                    floatx4 acc[2][2];
                    #pragma unroll
                    for (int i2 = 0; i2 < 2; ++i2)
                        #pragma unroll
                        for (int j2 = 0; j2 < 2; ++j2)
                            acc[i2][j2] = (floatx4){0.f, 0.f, 0.f, 0.f};
                    #pragma unroll
                    for (int kk = 0; kk < 4; ++kk)
                        #pragma unroll
                        for (int i2 = 0; i2 < 2; ++i2)
                            #pragma unroll
                            for (int j2 = 0; j2 < 2; ++j2)
                                acc[i2][j2] = __builtin_amdgcn_mfma_f32_16x16x32_fp8_fp8(
                                    afr[i2][kk], breg[jp * 2 + j2][kk], acc[i2][j2], 0, 0, 0);

                    const unsigned int inv0 = 1023u - (unsigned)(c0h + jp * 32 + m16);
                    const unsigned int inv1 = inv0 - 16u;
                    #pragma unroll
                    for (int i2 = 0; i2 < 2; ++i2)
                        #pragma unroll
                        for (int r = 0; r < 4; ++r) {
                            const int slot = (ihalf * 2 + i2) * 4 + r;
                            float cc0 = key_pack(acc[i2][0][r], inv0);
                            float cc1 = key_pack(acc[i2][1][r], inv1);
                            best[slot] = fmaxf(best[slot], fmaxf(cc0, cc1));
                        }
                }
            }
        }

        // cross-m16 butterfly (same rows, different cols)
        #pragma unroll
        for (int mask = 1; mask <= 8; mask <<= 1)
            #pragma unroll
            for (int s = 0; s < 16; ++s)
                best[s] = fmaxf(best[s], __shfl_xor(best[s], mask));

        if (m16 == 0) {
            #pragma unroll
            for (int s = 0; s < 16; ++s) {
                int i = s >> 2, rr = s & 3;
                int row = 16 * i + quad * 4 + rr;   // local row 0..63
                bv[wn][row] = best[s];
            }
        }
        __syncthreads();                     // bv visible; all As reads done

        // ---- combine 8 wave-slices; nf from partials; loss; reduce ----
        if (tid < 64) {
            float k01 = fmaxf(bv[0][tid], bv[1][tid]);
            float k23 = fmaxf(bv[2][tid], bv[3][tid]);
            float k45 = fmaxf(bv[4][tid], bv[5][tid]);
            float k67 = fmaxf(bv[6][tid], bv[7][tid]);
            float kmax = fmaxf(fmaxf(k01, k23), fmaxf(k45, k67));

            const float* np = &nfp[rt & 1][tid * 8];
            float s01 = np[0] + np[1], s23 = np[2] + np[3];
            float s45 = np[4] + np[5], s67 = np[6] + np[7];
            float ssq = (s01 + s23) + (s45 + s67);

            unsigned int ub = __builtin_bit_cast(unsigned int, kmax);
            int   ka = 1023 - (int)(ub & 1023u);
            float d  = __builtin_bit_cast(float, (ub & 0xFFFFFC00u) | 0x200u);
            float nf = fmaxf(sqrtf(ssq), 1e-12f);
            float na = cnorm[ka];
            float lsum = 1.0f - 2.0f * d * na / nf + na * na;
            #pragma unroll
            for (int m = 1; m <= 32; m <<= 1) lsum += __shfl_xor(lsum, m);
            if (tid == 0) atomicAdd(out, lsum / (float)N);
        }
        // no trailing barrier: next staging writes As (reads done pre-bar2)
        // and nfp[(rt+1)&1] (disjoint from nfp[rt&1] read here); bv rewritten
        // only after the next __syncthreads().
    }
}

extern "C" void kernel_launch(void* const* d_in, const int* in_sizes, int n_in,
                              void* d_out, int out_size, void* d_ws, size_t ws_size,
                              hipStream_t stream) {
    const float* feats   = (const float*)d_in[0];
    const float* centers = (const float*)d_in[1];
    const int N = in_sizes[0] / D;   // 131072
    const int K = in_sizes[1] / D;   // 1024

    unsigned char* chat = (unsigned char*)d_ws;                    // 1024*128 fp8 = 128 KB
    float* cnorm = (float*)((char*)d_ws + (size_t)K * D);          // K fp32
    float* out = (float*)d_out;

    const int smem = ROWT * D;               // 8192 B dynamic (~14.3 KB total)
    (void)hipFuncSetAttribute((const void*)cluster_main,
                              hipFuncAttributeMaxDynamicSharedMemorySize, smem);

    prep_centers<<<K, D, 0, stream>>>(centers, chat, cnorm, out);

    const int grid = 512;                    // 256 rows/block
    const int rtPer = (N / ROWT) / grid;     // 4 row tiles of 64
    cluster_main<<<grid, 512, smem, stream>>>(feats, chat, cnorm, out, N, rtPer);
}

// Round 6
// 137.117 us; speedup vs baseline: 1.2989x; 1.0521x over previous
//
#include <hip/hip_runtime.h>
#include <hip/hip_bf16.h>

// ClusterLoss fused kernel for MI355X (gfx950).  R13.
// Post-mortem R12: occupancy pattern across rounds (VGPR<=64 -> 35%, VGPR
// 80-84 -> 21%) says the 2nd block/CU stops co-residing once unified
// VGPR+AGPR crosses the 4-waves/SIMD bracket; with one 8-wave block per CU
// every latency is bare (23K cyc/rt vs 2.5K MFMA floor).
// R13 hides latency INSIDE the block: depth-1 pipeline, ONE barrier per rt.
//   - raw[4] regs prefetch next tile's feats during current MFMA phase.
//   - As double-buffered (2x8KB): convert+write of tile rt+1 runs before
//     MFMA(rt) on the other buffer.  bv parity-doubled, nfp per-rt slot ->
//     no second barrier needed (all cross-phase races checked).
//   - loop order ihalf->(half,jp): afr ds_reads 32->16/rt; breg loaded
//     per-jp (16 regs not 32), same L2 load count, lower peak pressure.
// Allocator rules (measured): 1024-thread or min-waves>=4 -> 64-VGPR pin +
// spill. Stay at 512 threads, __launch_bounds__(512, 1).
// loss_n = 1 - 2 d na/nf + na^2 (fp32 scalars).

#define D 128
#define ROWT 64
#define RT_MAX 4

typedef __attribute__((ext_vector_type(4))) float floatx4;

template <bool HI>
__device__ __forceinline__ unsigned int pk_fp8(float a, float b, unsigned int old) {
    return (unsigned int)__builtin_amdgcn_cvt_pk_fp8_f32(a, b, (int)old, HI);
}

__device__ __forceinline__ float key_pack(float v, unsigned int inv_k) {
    unsigned int u = __builtin_bit_cast(unsigned int, v);
    unsigned int r = (0x3FFu & inv_k) | (~0x3FFu & u);   // v_bfi_b32
    return __builtin_bit_cast(float, r);
}

// ---- Prep: normalize centers -> fp8 chat, store fp32 norms; zero d_out ----
__global__ void prep_centers(const float* __restrict__ centers,
                             unsigned char* __restrict__ chat,
                             float* __restrict__ cnorm,
                             float* __restrict__ out) {
    const int k = blockIdx.x;
    const int t = threadIdx.x;            // 128 threads, one per dim
    float v = centers[(size_t)k * D + t];
    float s = v * v;
    #pragma unroll
    for (int m = 1; m <= 32; m <<= 1) s += __shfl_xor(s, m);
    __shared__ float ws2[2];
    if ((t & 63) == 0) ws2[t >> 6] = s;
    __syncthreads();
    float total = ws2[0] + ws2[1];
    float n = sqrtf(total);
    float neff = fmaxf(n, 1e-12f);
    float q = v / neff;
    chat[(size_t)k * D + t] = (unsigned char)(pk_fp8<false>(q, q, 0u) & 0xFFu);
    if (t == 0) cnorm[k] = n;
    if (k == 0 && t == 0) out[0] = 0.0f;
}

// ---- Main ----
__global__ __launch_bounds__(512, 1) void cluster_main(
    const float* __restrict__ feats,        // [N][128] fp32
    const unsigned char* __restrict__ chat, // [1024][128] fp8 e4m3
    const float* __restrict__ cnorm,        // [1024] fp32
    float* __restrict__ out, int N, int rtPer) {

    extern __shared__ unsigned char lds[];
    unsigned char* As0 = lds;                // 8192 B, swizzled (64 rows)
    unsigned char* As1 = lds + ROWT * D;     // 8192 B, second buffer
    __shared__ float bv[2][8][64];           // per-wave keyed max, rt-parity
    __shared__ float nfp[RT_MAX][512];       // sumsq partials, per-rt slot

    const int tid  = threadIdx.x;            // 0..511, 8 waves
    const int lane = tid & 63;
    const int wn   = tid >> 6;               // wave = 64-center slice
    const int m16  = lane & 15;
    const int quad = lane >> 4;              // 0..3
    const int q1   = quad >> 1, q0 = quad & 1;
    const int m8   = m16 & 7;
    const int rowBase = blockIdx.x * (rtPer * ROWT);
    const int sr = tid >> 3;                 // staging row 0..63
    const int sc = tid & 7;                  // staging 16B fp8 chunk 0..7

    float4 raw[4];                           // prefetched feats (1 row-chunk)

    auto loadraw = [&](int rtIdx) {
        const float4* src =
            (const float4*)(feats + (size_t)(rowBase + rtIdx * ROWT + sr) * D + sc * 16);
        raw[0] = src[0]; raw[1] = src[1]; raw[2] = src[2]; raw[3] = src[3];
    };
    auto stage = [&](unsigned char* Adst, int rtIdx) {
        uint4 w;
        w.x = pk_fp8<true>(raw[0].z, raw[0].w, pk_fp8<false>(raw[0].x, raw[0].y, 0u));
        w.y = pk_fp8<true>(raw[1].z, raw[1].w, pk_fp8<false>(raw[1].x, raw[1].y, 0u));
        w.z = pk_fp8<true>(raw[2].z, raw[2].w, pk_fp8<false>(raw[2].x, raw[2].y, 0u));
        w.w = pk_fp8<true>(raw[3].z, raw[3].w, pk_fp8<false>(raw[3].x, raw[3].y, 0u));
        *(uint4*)&Adst[sr * D + ((sc ^ (sr & 7)) << 4)] = w;
        float sq = raw[0].x*raw[0].x + raw[0].y*raw[0].y + raw[0].z*raw[0].z + raw[0].w*raw[0].w;
        sq += raw[1].x*raw[1].x + raw[1].y*raw[1].y + raw[1].z*raw[1].z + raw[1].w*raw[1].w;
        sq += raw[2].x*raw[2].x + raw[2].y*raw[2].y + raw[2].z*raw[2].z + raw[2].w*raw[2].w;
        sq += raw[3].x*raw[3].x + raw[3].y*raw[3].y + raw[3].z*raw[3].z + raw[3].w*raw[3].w;
        nfp[rtIdx][tid] = sq;
    };

    // ---- Prologue: tile 0 staged, tile 1 in flight ----
    loadraw(0);
    stage(As0, 0);
    if (rtPer > 1) loadraw(1);
    __syncthreads();                         // As0 + nfp[0] visible

    #pragma unroll 1
    for (int rt = 0; rt < rtPer; ++rt) {
        unsigned char* Acur = (rt & 1) ? As1 : As0;
        unsigned char* Anxt = (rt & 1) ? As0 : As1;

        // pipeline: convert in-flight tile, then issue tile rt+2 loads
        if (rt + 1 < rtPer) stage(Anxt, rt + 1);
        if (rt + 2 < rtPer) loadraw(rt + 2);

        float best[16];                      // keyed floats, slot = ig*4 + r
        #pragma unroll
        for (int s = 0; s < 16; ++s) best[s] = -3.0e38f;

        // ---- barrier-free MFMA: 64 rows x 128 centers (this wave) ----
        #pragma unroll
        for (int ihalf = 0; ihalf < 2; ++ihalf) {
            long long afr[2][4];             // [i2][kk]
            #pragma unroll
            for (int i2 = 0; i2 < 2; ++i2) {
                const int r = (ihalf * 2 + i2) * 16 + m16;
                #pragma unroll
                for (int kk = 0; kk < 4; ++kk) {
                    int pc = (2 * kk + q1) ^ m8;
                    afr[i2][kk] = *(const long long*)&Acur[r * D + pc * 16 + q0 * 8];
                }
            }
            #pragma unroll
            for (int hp = 0; hp < 4; ++hp) { // (half, jp) pairs
                const int c0 = (hp >> 1) * 512 + wn * 64 + (hp & 1) * 32;
                long long breg[2][4];
                #pragma unroll
                for (int j2 = 0; j2 < 2; ++j2)
                    #pragma unroll
                    for (int kk = 0; kk < 4; ++kk)
                        breg[j2][kk] = *(const long long*)(chat
                            + (size_t)(c0 + j2 * 16 + m16) * D + kk * 32 + quad * 8);

                floatx4 acc[2][2];
                #pragma unroll
                for (int i2 = 0; i2 < 2; ++i2)
                    #pragma unroll
                    for (int j2 = 0; j2 < 2; ++j2)
                        acc[i2][j2] = (floatx4){0.f, 0.f, 0.f, 0.f};
                #pragma unroll
                for (int kk = 0; kk < 4; ++kk)
                    #pragma unroll
                    for (int i2 = 0; i2 < 2; ++i2)
                        #pragma unroll
                        for (int j2 = 0; j2 < 2; ++j2)
                            acc[i2][j2] = __builtin_amdgcn_mfma_f32_16x16x32_fp8_fp8(
                                afr[i2][kk], breg[j2][kk], acc[i2][j2], 0, 0, 0);

                const unsigned int inv0 = 1023u - (unsigned)(c0 + m16);
                const unsigned int inv1 = inv0 - 16u;
                #pragma unroll
                for (int i2 = 0; i2 < 2; ++i2)
                    #pragma unroll
                    for (int r = 0; r < 4; ++r) {
                        const int slot = (ihalf * 2 + i2) * 4 + r;
                        float cc0 = key_pack(acc[i2][0][r], inv0);
                        float cc1 = key_pack(acc[i2][1][r], inv1);
                        best[slot] = fmaxf(best[slot], fmaxf(cc0, cc1));
                    }
            }
        }

        // cross-m16 butterfly (same rows, different cols)
        #pragma unroll
        for (int mask = 1; mask <= 8; mask <<= 1)
            #pragma unroll
            for (int s = 0; s < 16; ++s)
                best[s] = fmaxf(best[s], __shfl_xor(best[s], mask));

        if (m16 == 0) {
            #pragma unroll
            for (int s = 0; s < 16; ++s) {
                int i = s >> 2, rr = s & 3;
                int row = 16 * i + quad * 4 + rr;   // local row 0..63
                bv[rt & 1][wn][row] = best[s];
            }
        }
        __syncthreads();   // bv[rt&1] + As[(rt+1)&1] + nfp[rt+1] visible;
                           // Acur reads done (safe to overwrite next iter)

        // ---- combine 8 wave-slices; nf from partials; loss; reduce ----
        if (tid < 64) {
            const float (*bvc)[64] = bv[rt & 1];
            float k01 = fmaxf(bvc[0][tid], bvc[1][tid]);
            float k23 = fmaxf(bvc[2][tid], bvc[3][tid]);
            float k45 = fmaxf(bvc[4][tid], bvc[5][tid]);
            float k67 = fmaxf(bvc[6][tid], bvc[7][tid]);
            float kmax = fmaxf(fmaxf(k01, k23), fmaxf(k45, k67));

            const float* np = &nfp[rt][tid * 8];
            float s01 = np[0] + np[1], s23 = np[2] + np[3];
            float s45 = np[4] + np[5], s67 = np[6] + np[7];
            float ssq = (s01 + s23) + (s45 + s67);

            unsigned int ub = __builtin_bit_cast(unsigned int, kmax);
            int   ka = 1023 - (int)(ub & 1023u);
            float d  = __builtin_bit_cast(float, (ub & 0xFFFFFC00u) | 0x200u);
            float nf = fmaxf(sqrtf(ssq), 1e-12f);
            float na = cnorm[ka];
            float lsum = 1.0f - 2.0f * d * na / nf + na * na;
            #pragma unroll
            for (int m = 1; m <= 32; m <<= 1) lsum += __shfl_xor(lsum, m);
            if (tid == 0) atomicAdd(out, lsum / (float)N);
        }
        // combine(rt) finishes before wave 0 reaches barrier(rt+1), and no
        // other wave can pass barrier(rt+1) without wave 0 -> writes that
        // touch bv[rt&1] (iter rt+2) can't start until combine is done.
    }
}

extern "C" void kernel_launch(void* const* d_in, const int* in_sizes, int n_in,
                              void* d_out, int out_size, void* d_ws, size_t ws_size,
                              hipStream_t stream) {
    const float* feats   = (const float*)d_in[0];
    const float* centers = (const float*)d_in[1];
    const int N = in_sizes[0] / D;   // 131072
    const int K = in_sizes[1] / D;   // 1024

    unsigned char* chat = (unsigned char*)d_ws;                    // 1024*128 fp8 = 128 KB
    float* cnorm = (float*)((char*)d_ws + (size_t)K * D);          // K fp32
    float* out = (float*)d_out;

    const int smem = 2 * ROWT * D;           // 16384 B dynamic (~28.7 KB total)
    (void)hipFuncSetAttribute((const void*)cluster_main,
                              hipFuncAttributeMaxDynamicSharedMemorySize, smem);

    prep_centers<<<K, D, 0, stream>>>(centers, chat, cnorm, out);

    const int grid = 512;                    // 256 rows/block
    const int rtPer = (N / ROWT) / grid;     // 4 row tiles of 64 (== RT_MAX)
    cluster_main<<<grid, 512, smem, stream>>>(feats, chat, cnorm, out, N, rtPer);
}

// Round 7
// 119.328 us; speedup vs baseline: 1.4926x; 1.1491x over previous
//
#include <hip/hip_runtime.h>

// ClusterLoss fused kernel for MI355X (gfx950).  R14.
// Cross-round evidence (R7-R13): any 8-wave barrier-synced block runs alone
// on its CU (Occupancy ~21% whenever VGPR>=80, independent of LDS 28..147KB)
// and lockstep barriers expose every phase latency -> MfmaUtil ceiling ~18%.
// R14 deletes the block structure: WAVE-AUTONOMOUS kernel, zero barriers.
//   - 4096 waves (1024 blocks x 256 thr); each wave owns one 32-row tile and
//     sweeps ALL 1024 centers.
//   - A-tile staged by the wave into its private 4KB LDS slice (same swizzle
//     and fragment math as R7-R13, verified); cross-lane visibility via
//     inline s_waitcnt lgkmcnt(0), no __syncthreads anywhere.
//   - B re-laid-out by prep into frag-ordered stream bws[g][lane][kk]:
//     per 16-center group each lane reads its 32B as two dwordx4 (wave reads
//     2KB contiguous, L2-hot). 128 loads : 512 MFMAs per tile.
//   - wave-local sumsq (3 shuffles), wave-local argmax/loss epilogue,
//     per-wave partial to wsum[]; reduce_out kernel sums -> atomics deleted.
// Allocator rules (measured): 1024-thr block or launch_bounds min-waves>=2
// pins 64 VGPR + scratch spill. Use (256,1).
// loss_n = 1 - 2 d na/nf + na^2 (fp32 scalars).

#define D 128
#define TROWS 32

typedef __attribute__((ext_vector_type(4))) float floatx4;
typedef __attribute__((ext_vector_type(2))) long long llx2;

template <bool HI>
__device__ __forceinline__ unsigned int pk_fp8(float a, float b, unsigned int old) {
    return (unsigned int)__builtin_amdgcn_cvt_pk_fp8_f32(a, b, (int)old, HI);
}

__device__ __forceinline__ float key_pack(float v, unsigned int inv_k) {
    unsigned int u = __builtin_bit_cast(unsigned int, v);
    unsigned int r = (0x3FFu & inv_k) | (~0x3FFu & u);   // v_bfi_b32
    return __builtin_bit_cast(float, r);
}

// ---- Prep: normalize centers -> fp8, scattered into frag-ordered bws ----
// bws byte layout: ((g*64 + lane)*4 + kk)*8 + b  ==  chat[g*16 + (lane&15)]
//                                                    [kk*32 + (lane>>4)*8 + b]
__global__ void prep_centers(const float* __restrict__ centers,
                             unsigned char* __restrict__ bws,
                             float* __restrict__ cnorm) {
    const int k = blockIdx.x;
    const int t = threadIdx.x;            // 128 threads, one per dim
    float v = centers[(size_t)k * D + t];
    float s = v * v;
    #pragma unroll
    for (int m = 1; m <= 32; m <<= 1) s += __shfl_xor(s, m);
    __shared__ float ws2[2];
    if ((t & 63) == 0) ws2[t >> 6] = s;
    __syncthreads();
    float total = ws2[0] + ws2[1];
    float n = sqrtf(total);
    float q = v / fmaxf(n, 1e-12f);
    const int kk = t >> 5, quad = (t >> 3) & 3, b = t & 7;
    const int lane = (k & 15) + (quad << 4);
    const int g = k >> 4;
    bws[(((size_t)g * 64 + lane) * 4 + kk) * 8 + b] =
        (unsigned char)(pk_fp8<false>(q, q, 0u) & 0xFFu);
    if (t == 0) cnorm[k] = n;
}

// ---- Main: wave-autonomous, no barriers ----
__global__ __launch_bounds__(256, 1) void cluster_main(
    const float* __restrict__ feats,        // [N][128] fp32
    const unsigned char* __restrict__ bws,  // frag-ordered fp8 centers, 128 KB
    const float* __restrict__ cnorm,        // [1024] fp32
    float* __restrict__ wsum, int nTiles) {

    extern __shared__ unsigned char lds[];
    const int tid  = threadIdx.x;            // 0..255, 4 waves
    const int lane = tid & 63;
    const int w    = tid >> 6;
    unsigned char* As = lds + w * (TROWS * D);   // private 4 KB slice
    __shared__ float nf_w[4][32];
    __shared__ float bm_w[4][32];

    const int m16  = lane & 15;
    const int quad = lane >> 4;              // 0..3
    const int q1   = quad >> 1, q0 = quad & 1;
    const int m8   = m16 & 7;
    const int srow = lane >> 3;              // staging row offset 0..7
    const int sc   = lane & 7;               // staging 16-float chunk 0..7

    const int nWaves = gridDim.x * 4;
    const int gw = blockIdx.x * 4 + w;

    float lossAcc = 0.0f;

    for (int t = gw; t < nTiles; t += nWaves) {
        const int row0 = t * TROWS;

        // ---- Stage A: 32 rows x 128 dims; lane-local sumsq partials ----
        float sq[4];
        #pragma unroll
        for (int s = 0; s < 4; ++s) {
            const int r = s * 8 + srow;
            const float4* src =
                (const float4*)(feats + (size_t)(row0 + r) * D + sc * 16);
            float4 v0 = src[0], v1 = src[1], v2 = src[2], v3 = src[3];
            uint4 wd;
            wd.x = pk_fp8<true>(v0.z, v0.w, pk_fp8<false>(v0.x, v0.y, 0u));
            wd.y = pk_fp8<true>(v1.z, v1.w, pk_fp8<false>(v1.x, v1.y, 0u));
            wd.z = pk_fp8<true>(v2.z, v2.w, pk_fp8<false>(v2.x, v2.y, 0u));
            wd.w = pk_fp8<true>(v3.z, v3.w, pk_fp8<false>(v3.x, v3.y, 0u));
            *(uint4*)&As[r * D + ((sc ^ (r & 7)) << 4)] = wd;
            float a = v0.x*v0.x + v0.y*v0.y + v0.z*v0.z + v0.w*v0.w;
            a += v1.x*v1.x + v1.y*v1.y + v1.z*v1.z + v1.w*v1.w;
            a += v2.x*v2.x + v2.y*v2.y + v2.z*v2.z + v2.w*v2.w;
            a += v3.x*v3.x + v3.y*v3.y + v3.z*v3.z + v3.w*v3.w;
            sq[s] = a;
        }
        // sum over chunk dim (lanes' low 3 bits) -> rows' sumsq
        #pragma unroll
        for (int m = 1; m <= 4; m <<= 1)
            #pragma unroll
            for (int s = 0; s < 4; ++s) sq[s] += __shfl_xor(sq[s], m);
        if (sc == 0) {
            #pragma unroll
            for (int s = 0; s < 4; ++s) nf_w[w][s * 8 + srow] = sq[s];
        }
        asm volatile("s_waitcnt lgkmcnt(0)" ::: "memory");  // As+nf_w visible

        // ---- A fragments (rows i2*16+m16) ----
        long long afr[2][4];
        #pragma unroll
        for (int i2 = 0; i2 < 2; ++i2) {
            const int r = i2 * 16 + m16;
            #pragma unroll
            for (int kk = 0; kk < 4; ++kk) {
                int pc = (2 * kk + q1) ^ m8;
                afr[i2][kk] = *(const long long*)&As[r * D + pc * 16 + q0 * 8];
            }
        }

        float best[8];                       // slot = i2*4 + r
        #pragma unroll
        for (int s = 0; s < 8; ++s) best[s] = -3.0e38f;

        // ---- sweep all 1024 centers: 32 pairs of 16-center groups ----
        #pragma unroll 2
        for (int g2 = 0; g2 < 32; ++g2) {
            const int g = g2 * 2;
            const unsigned char* p0 = bws + ((size_t)(g * 64 + lane)) * 32;
            const unsigned char* p1 = p0 + 64 * 32;
            llx2 b0lo = *(const llx2*)(p0);
            llx2 b0hi = *(const llx2*)(p0 + 16);
            llx2 b1lo = *(const llx2*)(p1);
            llx2 b1hi = *(const llx2*)(p1 + 16);
            long long br0[4] = { b0lo[0], b0lo[1], b0hi[0], b0hi[1] };
            long long br1[4] = { b1lo[0], b1lo[1], b1hi[0], b1hi[1] };

            floatx4 a00 = (floatx4){0.f,0.f,0.f,0.f};
            floatx4 a01 = (floatx4){0.f,0.f,0.f,0.f};
            floatx4 a10 = (floatx4){0.f,0.f,0.f,0.f};
            floatx4 a11 = (floatx4){0.f,0.f,0.f,0.f};
            #pragma unroll
            for (int kk = 0; kk < 4; ++kk) {
                a00 = __builtin_amdgcn_mfma_f32_16x16x32_fp8_fp8(afr[0][kk], br0[kk], a00, 0, 0, 0);
                a01 = __builtin_amdgcn_mfma_f32_16x16x32_fp8_fp8(afr[0][kk], br1[kk], a01, 0, 0, 0);
                a10 = __builtin_amdgcn_mfma_f32_16x16x32_fp8_fp8(afr[1][kk], br0[kk], a10, 0, 0, 0);
                a11 = __builtin_amdgcn_mfma_f32_16x16x32_fp8_fp8(afr[1][kk], br1[kk], a11, 0, 0, 0);
            }

            const unsigned int inv0 = 1023u - (unsigned)(g * 16 + m16);
            const unsigned int inv1 = inv0 - 16u;
            #pragma unroll
            for (int r = 0; r < 4; ++r) {
                best[r]     = fmaxf(best[r],
                               fmaxf(key_pack(a00[r], inv0), key_pack(a01[r], inv1)));
                best[4 + r] = fmaxf(best[4 + r],
                               fmaxf(key_pack(a10[r], inv0), key_pack(a11[r], inv1)));
            }
        }

        // cross-m16 butterfly: per (quad,i2,r) max over all centers
        #pragma unroll
        for (int mask = 1; mask <= 8; mask <<= 1)
            #pragma unroll
            for (int s = 0; s < 8; ++s)
                best[s] = fmaxf(best[s], __shfl_xor(best[s], mask));

        if (m16 == 0) {
            #pragma unroll
            for (int s = 0; s < 8; ++s) {
                int row = (s >> 2) * 16 + quad * 4 + (s & 3);
                bm_w[w][row] = best[s];
            }
        }
        asm volatile("s_waitcnt lgkmcnt(0)" ::: "memory");  // bm_w visible

        // ---- decode + loss, 32 rows on 32 lanes; wave reduce ----
        float lsum = 0.0f;
        if (lane < 32) {
            const int row = lane;
            unsigned int ub = __builtin_bit_cast(unsigned int, bm_w[w][row]);
            int   ka = 1023 - (int)(ub & 1023u);
            float d  = __builtin_bit_cast(float, (ub & 0xFFFFFC00u) | 0x200u);
            float nf = fmaxf(sqrtf(nf_w[w][row]), 1e-12f);
            float na = cnorm[ka];
            lsum = 1.0f - 2.0f * d * na / nf + na * na;
        }
        #pragma unroll
        for (int m = 1; m <= 32; m <<= 1) lsum += __shfl_xor(lsum, m);
        lossAcc += lsum;
    }

    if (lane == 0) wsum[gw] = lossAcc;
}

// ---- Final: sum 4096 per-wave partials -> out[0] ----
__global__ void reduce_out(const float* __restrict__ wsum,
                           float* __restrict__ out, int nW, float invN) {
    float s = 0.0f;
    for (int i = threadIdx.x; i < (nW >> 2); i += 256) {
        float4 v = ((const float4*)wsum)[i];
        s += (v.x + v.y) + (v.z + v.w);
    }
    #pragma unroll
    for (int m = 1; m <= 32; m <<= 1) s += __shfl_xor(s, m);
    __shared__ float ws4[4];
    if ((threadIdx.x & 63) == 0) ws4[threadIdx.x >> 6] = s;
    __syncthreads();
    if (threadIdx.x == 0)
        out[0] = ((ws4[0] + ws4[1]) + (ws4[2] + ws4[3])) * invN;
}

extern "C" void kernel_launch(void* const* d_in, const int* in_sizes, int n_in,
                              void* d_out, int out_size, void* d_ws, size_t ws_size,
                              hipStream_t stream) {
    const float* feats   = (const float*)d_in[0];
    const float* centers = (const float*)d_in[1];
    const int N = in_sizes[0] / D;   // 131072
    const int K = in_sizes[1] / D;   // 1024

    unsigned char* bws = (unsigned char*)d_ws;                     // 128 KB
    float* cnorm = (float*)((char*)d_ws + (size_t)K * D);          // 4 KB
    float* wsum  = (float*)((char*)d_ws + (size_t)K * D + 4096);   // 16 KB
    float* out = (float*)d_out;

    prep_centers<<<K, D, 0, stream>>>(centers, bws, cnorm);

    const int grid = 1024;                   // 4096 waves == 4096 tiles
    const int nTiles = N / TROWS;
    cluster_main<<<grid, 256, 4 * TROWS * D, stream>>>(feats, bws, cnorm, wsum, nTiles);

    reduce_out<<<1, 256, 0, stream>>>(wsum, out, grid * 4, 1.0f / (float)N);
}